// Round 1
// baseline (1494.585 us; speedup 1.0000x reference)
//
#include <hip/hip_runtime.h>

// GCN-TCN unit, fp32 baseline.
// Shapes: N=32, C=128, T=256, V=25, K=5.
//
// Pipeline:
//   k0: zero stats, transpose Wd -> WdT[c][o], Wt -> WtT[(i*5+k)][o]
//   k1: y0[n,o,t,v] = sum_c Wd[o,c] * (sum_w x[n,c,t,w] PA[w,v]) + bd[o]
//       -> ws, + per-(n,o) sum/sumsq atomics (statsY)
//   k3: z0[n,o,t,v] = sum_{i,k} relu(inorm(y0)[n,i,|t+k-4|,v] + x[...]) * Wt[o,i,k] + bt[o]
//       -> d_out, + statsZ atomics
//   k4: out = relu((z0 - m)*rstd + x)   in-place on d_out

#define NBATCH 32
#define CH     128
#define TDIM   256
#define VDIM   25
#define KT     5
#define PLANE  (TDIM*VDIM)          // 6400
#define EPSF   1e-5f
#define INV_PLANE (1.0f/6400.0f)

// ---------------- K0: init stats + transpose weights ----------------
__global__ __launch_bounds__(256) void k0_init(
    const float* __restrict__ Wd, const float* __restrict__ Wt,
    float* __restrict__ statsY, float* __restrict__ statsZ,
    float* __restrict__ WdT, float* __restrict__ WtT)
{
    int i = blockIdx.x * 256 + threadIdx.x;       // grid covers exactly 114688
    if (i < 8192) {
        statsY[i] = 0.f;
    } else if (i < 16384) {
        statsZ[i - 8192] = 0.f;
    } else if (i < 32768) {
        int j = i - 16384;                        // WdT[c*128+o] = Wd[o*128+c]
        int c = j >> 7, o = j & 127;
        WdT[j] = Wd[o * CH + c];
    } else {
        int j = i - 32768;                        // WtT[(i*5+k)*128+o] = Wt[o][i][k]
        int o = j & 127;
        int ik = j >> 7;
        int k = ik % KT;
        int ii = ik / KT;
        WtT[j] = Wt[(o * CH + ii) * KT + k];
    }
}

// ---------------- K1: GCN (x@PA then channel GEMM) ----------------
// grid (64, 32): blockIdx.x = t-chunk (4 t's), blockIdx.y = n. 256 threads.
// Output tile: 128 o x (4 t x 32 v-padded) = 128x128 cols, 8x8 micro per thread.
__global__ __launch_bounds__(256) void k1_gcn(
    const float* __restrict__ x, const float* __restrict__ PA,
    const float* __restrict__ WdT, const float* __restrict__ bd,
    float* __restrict__ y0, float* __restrict__ statsY)
{
    __shared__ float sX[16][100];   // raw x chunk: 16 c x (4t x 25v)
    __shared__ float sW[16][128];   // WdT chunk:   16 c x 128 o
    __shared__ float sG[16][128];   // transformed: 16 c x (4t x 32v padded)

    const int tid = threadIdx.x;
    const int n   = blockIdx.y;
    const int t0  = blockIdx.x * 4;
    const int tx  = tid & 15;       // col = tx + 16*jc
    const int ty  = tid >> 4;       // o   = ty*8 + jo  (vector a-loads)

    const int colT = tid & 127;     // fixed transform column for this thread
    const int vT   = colT & 31;
    const int tlT  = colT >> 5;

    // PA column for this thread's v (zeros for padded v>=25 -> g=0 automatically)
    float pa[VDIM];
#pragma unroll
    for (int w = 0; w < VDIM; ++w)
        pa[w] = (vT < VDIM) ? PA[w * VDIM + vT] : 0.f;

    float acc[8][8];
#pragma unroll
    for (int a = 0; a < 8; ++a)
#pragma unroll
        for (int b = 0; b < 8; ++b) acc[a][b] = 0.f;

    const int xbase0 = (n * CH) * PLANE + t0 * VDIM;

    for (int cb = 0; cb < 8; ++cb) {
        __syncthreads();
        // stage x: 16 c x 100 floats (contiguous per c-row)
        for (int i = tid; i < 1600; i += 256) {
            int cc = i / 100;
            int r  = i - cc * 100;
            sX[cc][r] = x[xbase0 + (cb * 16 + cc) * PLANE + r];
        }
        // stage WdT chunk (linear, coalesced)
        for (int i = tid; i < 2048; i += 256) {
            sW[i >> 7][i & 127] = WdT[cb * 2048 + i];
        }
        __syncthreads();
        // transform x -> g for this chunk: each thread keeps fixed (tl, v), walks cc
#pragma unroll
        for (int s = 0; s < 8; ++s) {
            int cc = (tid >> 7) + 2 * s;
            float g = 0.f;
#pragma unroll
            for (int w = 0; w < VDIM; ++w)
                g += sX[cc][tlT * VDIM + w] * pa[w];
            sG[cc][colT] = g;
        }
        __syncthreads();
        // GEMM over 16 c
#pragma unroll
        for (int cc = 0; cc < 16; ++cc) {
            float a0[8], b0[8];
#pragma unroll
            for (int jo = 0; jo < 8; ++jo) a0[jo] = sW[cc][ty * 8 + jo];
#pragma unroll
            for (int jc = 0; jc < 8; ++jc) b0[jc] = sG[cc][tx + 16 * jc];
#pragma unroll
            for (int jo = 0; jo < 8; ++jo)
#pragma unroll
                for (int jc = 0; jc < 8; ++jc)
                    acc[jo][jc] += a0[jo] * b0[jc];
        }
    }

    // epilogue: bias, compact store, stats partials
    float bdv[8];
#pragma unroll
    for (int jo = 0; jo < 8; ++jo) bdv[jo] = bd[ty * 8 + jo];

    float s1[8], s2[8];
#pragma unroll
    for (int jo = 0; jo < 8; ++jo) { s1[jo] = 0.f; s2[jo] = 0.f; }

#pragma unroll
    for (int jc = 0; jc < 8; ++jc) {
        int col = tx + 16 * jc;
        int t   = t0 + (col >> 5);
        int v   = col & 31;
        if (v < VDIM) {
#pragma unroll
            for (int jo = 0; jo < 8; ++jo) {
                int o = ty * 8 + jo;
                float val = acc[jo][jc] + bdv[jo];
                y0[(n * CH + o) * PLANE + t * VDIM + v] = val;
                s1[jo] += val;
                s2[jo] += val * val;
            }
        }
    }
    // reduce across the 16-lane tx group (lane = tid&63, tx = lane&15)
#pragma unroll
    for (int jo = 0; jo < 8; ++jo) {
#pragma unroll
        for (int m = 1; m <= 8; m <<= 1) {
            s1[jo] += __shfl_xor(s1[jo], m, 64);
            s2[jo] += __shfl_xor(s2[jo], m, 64);
        }
    }
    if (tx == 0) {
#pragma unroll
        for (int jo = 0; jo < 8; ++jo) {
            int o = ty * 8 + jo;
            atomicAdd(&statsY[(n * CH + o) * 2 + 0], s1[jo]);
            atomicAdd(&statsY[(n * CH + o) * 2 + 1], s2[jo]);
        }
    }
}

// ---------------- K3: TCN conv as GEMM over (i,k), K=640 ----------------
// grid (32, 32): blockIdx.x = t-chunk (8 t's), blockIdx.y = n. 512 threads.
// Output tile: 128 o x (8 t x 32 v-padded) = 128x256 cols, 8x8 micro per thread.
__global__ __launch_bounds__(512) void k3_tcn(
    const float* __restrict__ x, const float* __restrict__ y0,
    const float* __restrict__ WtT, const float* __restrict__ bt,
    const float* __restrict__ statsY,
    float* __restrict__ zout, float* __restrict__ statsZ)
{
    __shared__ float  sY[12 * 256];   // [tl][ii*32+v], tl in [0,12): rows t0-4 .. t0+7
    __shared__ float  sWf[8 * 640];   // [ii][k*128+o]
    __shared__ float2 sMR[CH];        // per-channel (mean, rstd) of y0

    const int tid = threadIdx.x;      // 0..511
    const int n   = blockIdx.y;
    const int t0  = blockIdx.x * 8;
    const int tx  = tid & 31;         // col = tx + 32*jc  -> v = tx, t-offset = jc
    const int ty  = tid >> 5;         // o   = ty*8 + jo

    if (tid < CH) {
        float a = statsY[(n * CH + tid) * 2 + 0];
        float b = statsY[(n * CH + tid) * 2 + 1];
        float m = a * INV_PLANE;
        float var = b * INV_PLANE - m * m;
        sMR[tid] = make_float2(m, rsqrtf(var + EPSF));
    }

    float acc[8][8];
#pragma unroll
    for (int a = 0; a < 8; ++a)
#pragma unroll
        for (int b = 0; b < 8; ++b) acc[a][b] = 0.f;

    for (int ib = 0; ib < 16; ++ib) {
        __syncthreads();
        // stage yhat tile: 12 t-rows x 8 i x 32 v (reflect |t0-4+tl|, norm+res+relu on the fly)
        for (int i = tid; i < 3072; i += 512) {
            int tl  = i >> 8;
            int rem = i & 255;
            int ii  = rem >> 5;
            int v   = rem & 31;
            int ic  = ib * 8 + ii;
            int sr  = t0 - 4 + tl;
            int s   = sr < 0 ? -sr : sr;          // reflect pad
            float val = 0.f;
            if (v < VDIM) {
                int g = (n * CH + ic) * PLANE + s * VDIM + v;
                float2 mr = sMR[ic];
                float yv = (y0[g] - mr.x) * mr.y + x[g];
                val = fmaxf(yv, 0.f);
            }
            sY[i] = val;                           // i == tl*256 + ii*32 + v
        }
        // stage weights: pure linear copy thanks to WtT layout
        for (int i = tid; i < 5120; i += 512) {
            sWf[i] = WtT[ib * 5120 + i];
        }
        __syncthreads();
#pragma unroll
        for (int ii = 0; ii < 8; ++ii) {
#pragma unroll
            for (int k = 0; k < KT; ++k) {
                float a0[8], b0[8];
#pragma unroll
                for (int jo = 0; jo < 8; ++jo)
                    a0[jo] = sWf[ii * 640 + k * 128 + ty * 8 + jo];
#pragma unroll
                for (int jc = 0; jc < 8; ++jc)
                    b0[jc] = sY[(jc + k) * 256 + ii * 32 + tx];
#pragma unroll
                for (int jo = 0; jo < 8; ++jo)
#pragma unroll
                    for (int jc = 0; jc < 8; ++jc)
                        acc[jo][jc] += a0[jo] * b0[jc];
            }
        }
    }

    // epilogue: bias, compact store to d_out, stats partials
    float btv[8];
#pragma unroll
    for (int jo = 0; jo < 8; ++jo) btv[jo] = bt[ty * 8 + jo];

    float s1[8], s2[8];
#pragma unroll
    for (int jo = 0; jo < 8; ++jo) { s1[jo] = 0.f; s2[jo] = 0.f; }

    if (tx < VDIM) {
#pragma unroll
        for (int jc = 0; jc < 8; ++jc) {
            int t = t0 + jc;
#pragma unroll
            for (int jo = 0; jo < 8; ++jo) {
                int o = ty * 8 + jo;
                float val = acc[jo][jc] + btv[jo];
                zout[(n * CH + o) * PLANE + t * VDIM + tx] = val;
                s1[jo] += val;
                s2[jo] += val * val;
            }
        }
    }
    // reduce across the 32-lane tx group
#pragma unroll
    for (int jo = 0; jo < 8; ++jo) {
#pragma unroll
        for (int m = 1; m <= 16; m <<= 1) {
            s1[jo] += __shfl_xor(s1[jo], m, 64);
            s2[jo] += __shfl_xor(s2[jo], m, 64);
        }
    }
    if (tx == 0) {
#pragma unroll
        for (int jo = 0; jo < 8; ++jo) {
            int o = ty * 8 + jo;
            atomicAdd(&statsZ[(n * CH + o) * 2 + 0], s1[jo]);
            atomicAdd(&statsZ[(n * CH + o) * 2 + 1], s2[jo]);
        }
    }
}

// ---------------- K4: out = relu(inorm(z0) + x), in-place on d_out ----------------
__global__ __launch_bounds__(256) void k4_final(
    const float* __restrict__ x, const float* __restrict__ statsZ,
    float* __restrict__ out)
{
    int i4 = blockIdx.x * 256 + threadIdx.x;      // grid covers exactly 6553600 float4s
    int p  = i4 / 1600;                           // plane index (6400/4 per plane)
    float a = statsZ[p * 2 + 0], b = statsZ[p * 2 + 1];
    float m = a * INV_PLANE;
    float r = rsqrtf(b * INV_PLANE - m * m + EPSF);
    float4 z  = ((const float4*)out)[i4];
    float4 xv = ((const float4*)x)[i4];
    float4 o;
    o.x = fmaxf((z.x - m) * r + xv.x, 0.f);
    o.y = fmaxf((z.y - m) * r + xv.y, 0.f);
    o.z = fmaxf((z.z - m) * r + xv.z, 0.f);
    o.w = fmaxf((z.w - m) * r + xv.w, 0.f);
    ((float4*)out)[i4] = o;
}

extern "C" void kernel_launch(void* const* d_in, const int* in_sizes, int n_in,
                              void* d_out, int out_size, void* d_ws, size_t ws_size,
                              hipStream_t stream) {
    const float* x  = (const float*)d_in[0];
    const float* PA = (const float*)d_in[1];
    const float* Wd = (const float*)d_in[2];
    const float* bd = (const float*)d_in[3];
    const float* Wt = (const float*)d_in[4];
    const float* bt = (const float*)d_in[5];
    float* out = (float*)d_out;

    float* ws     = (float*)d_ws;
    float* y0     = ws;                      // 26,214,400 floats
    float* statsY = y0 + 26214400;           // 8,192
    float* statsZ = statsY + 8192;           // 8,192
    float* WdT    = statsZ + 8192;           // 16,384
    float* WtT    = WdT + 16384;             // 81,920   (total ~100.4 MiB)

    k0_init<<<dim3(448), dim3(256), 0, stream>>>(Wd, Wt, statsY, statsZ, WdT, WtT);
    k1_gcn<<<dim3(64, 32), dim3(256), 0, stream>>>(x, PA, WdT, bd, y0, statsY);
    k3_tcn<<<dim3(32, 32), dim3(512), 0, stream>>>(x, y0, WtT, bt, statsY, out, statsZ);
    k4_final<<<dim3(25600), dim3(256), 0, stream>>>(x, statsZ, out);
}

// Round 2
// 855.424 us; speedup vs baseline: 1.7472x; 1.7472x over previous
//
#include <hip/hip_runtime.h>

// GCN-TCN unit. k1 fp32 register-tiled GEMM; k3 bf16 MFMA implicit-GEMM conv.
// Shapes: N=32, C=128, T=256, V=25, K=5.

typedef unsigned short u16;
typedef unsigned int   u32;

using short8  = __attribute__((ext_vector_type(8))) short;
using floatx4 = __attribute__((ext_vector_type(4))) float;

#define NBATCH 32
#define CH     128
#define TDIM   256
#define VDIM   25
#define KT     5
#define PLANE  6400
#define EPSF   1e-5f
#define INV_PLANE (1.0f/6400.0f)

__device__ __forceinline__ u16 f2bf(float f) {          // RNE fp32 -> bf16
    u32 u = __float_as_uint(f);
    return (u16)((u + 0x7fffu + ((u >> 16) & 1u)) >> 16);
}
__device__ __forceinline__ float bf2f(u16 h) {
    return __uint_as_float(((u32)h) << 16);
}
__device__ __forceinline__ void gload_lds16(const void* g, void* l) {
    __builtin_amdgcn_global_load_lds(
        (const __attribute__((address_space(1))) u32*)g,
        (__attribute__((address_space(3))) u32*)l, 16, 0, 0);
}

// ---------------- K0: init stats + weight repack ----------------
// statsY[8192] | statsZ[8192] | WdT[16384] fp32 | Wt_b[81920] bf16 [ic][tap][o][i32]
__global__ __launch_bounds__(256) void k0_init(
    const float* __restrict__ Wd, const float* __restrict__ Wt,
    float* __restrict__ statsY, float* __restrict__ statsZ,
    float* __restrict__ WdT, u16* __restrict__ Wt_b)
{
    int i = blockIdx.x * 256 + threadIdx.x;       // grid covers exactly 114688
    if (i < 8192) {
        statsY[i] = 0.f;
    } else if (i < 16384) {
        statsZ[i - 8192] = 0.f;
    } else if (i < 32768) {
        int j = i - 16384;                        // WdT[c*128+o] = Wd[o*128+c]
        int c = j >> 7, o = j & 127;
        WdT[j] = Wd[o * CH + c];
    } else {
        int j  = i - 32768;                       // [ic][tap][o][il]
        int il = j & 31;
        int o  = (j >> 5) & 127;
        int r2 = j >> 12;                         // ic*5 + tap
        int tap = r2 % KT;
        int ic  = r2 / KT;
        int ig  = ic * 32 + il;
        Wt_b[j] = f2bf(Wt[(o * CH + ig) * KT + tap]);
    }
}

// ---------------- K1: GCN (x@PA then channel GEMM), fp32, y0 stored bf16 ----------------
__global__ __launch_bounds__(256) void k1_gcn(
    const float* __restrict__ x, const float* __restrict__ PA,
    const float* __restrict__ WdT, const float* __restrict__ bd,
    u16* __restrict__ y0b, float* __restrict__ statsY)
{
    __shared__ float sX[16][100];
    __shared__ float sW[16][128];
    __shared__ float sG[16][128];

    const int tid = threadIdx.x;
    const int n   = blockIdx.y;
    const int t0  = blockIdx.x * 4;
    const int tx  = tid & 15;
    const int ty  = tid >> 4;

    const int colT = tid & 127;
    const int vT   = colT & 31;
    const int tlT  = colT >> 5;

    float pa[VDIM];
#pragma unroll
    for (int w = 0; w < VDIM; ++w)
        pa[w] = (vT < VDIM) ? PA[w * VDIM + vT] : 0.f;

    float acc[8][8];
#pragma unroll
    for (int a = 0; a < 8; ++a)
#pragma unroll
        for (int b = 0; b < 8; ++b) acc[a][b] = 0.f;

    const int xbase0 = (n * CH) * PLANE + t0 * VDIM;

    for (int cb = 0; cb < 8; ++cb) {
        __syncthreads();
        for (int i = tid; i < 1600; i += 256) {
            int cc = i / 100;
            int r  = i - cc * 100;
            sX[cc][r] = x[xbase0 + (cb * 16 + cc) * PLANE + r];
        }
        for (int i = tid; i < 2048; i += 256)
            sW[i >> 7][i & 127] = WdT[cb * 2048 + i];
        __syncthreads();
#pragma unroll
        for (int s = 0; s < 8; ++s) {
            int cc = (tid >> 7) + 2 * s;
            float g = 0.f;
#pragma unroll
            for (int w = 0; w < VDIM; ++w)
                g += sX[cc][tlT * VDIM + w] * pa[w];
            sG[cc][colT] = g;
        }
        __syncthreads();
#pragma unroll
        for (int cc = 0; cc < 16; ++cc) {
            float a0[8], b0[8];
#pragma unroll
            for (int jo = 0; jo < 8; ++jo) a0[jo] = sW[cc][ty * 8 + jo];
#pragma unroll
            for (int jc = 0; jc < 8; ++jc) b0[jc] = sG[cc][tx + 16 * jc];
#pragma unroll
            for (int jo = 0; jo < 8; ++jo)
#pragma unroll
                for (int jc = 0; jc < 8; ++jc)
                    acc[jo][jc] += a0[jo] * b0[jc];
        }
    }

    float bdv[8];
#pragma unroll
    for (int jo = 0; jo < 8; ++jo) bdv[jo] = bd[ty * 8 + jo];

    float s1[8], s2[8];
#pragma unroll
    for (int jo = 0; jo < 8; ++jo) { s1[jo] = 0.f; s2[jo] = 0.f; }

#pragma unroll
    for (int jc = 0; jc < 8; ++jc) {
        int col = tx + 16 * jc;
        int t   = t0 + (col >> 5);
        int v   = col & 31;
        if (v < VDIM) {
#pragma unroll
            for (int jo = 0; jo < 8; ++jo) {
                int o = ty * 8 + jo;
                float val = acc[jo][jc] + bdv[jo];
                y0b[(n * CH + o) * PLANE + t * VDIM + v] = f2bf(val);
                s1[jo] += val;
                s2[jo] += val * val;
            }
        }
    }
#pragma unroll
    for (int jo = 0; jo < 8; ++jo) {
#pragma unroll
        for (int m = 1; m <= 8; m <<= 1) {
            s1[jo] += __shfl_xor(s1[jo], m, 64);
            s2[jo] += __shfl_xor(s2[jo], m, 64);
        }
    }
    if (tx == 0) {
#pragma unroll
        for (int jo = 0; jo < 8; ++jo) {
            int o = ty * 8 + jo;
            atomicAdd(&statsY[(n * CH + o) * 2 + 0], s1[jo]);
            atomicAdd(&statsY[(n * CH + o) * 2 + 1], s2[jo]);
        }
    }
}

// ---------------- K2: yhat = relu(inorm(y0)+x) -> bf16 transposed [n][ic][col][i32] ----------------
// grid (25, 128): blockIdx.x = 256-col chunk, blockIdx.y = n*4+ic. 256 threads.
__global__ __launch_bounds__(256) void k2_yhat(
    const u16* __restrict__ y0b, const float* __restrict__ x,
    const float* __restrict__ statsY, u16* __restrict__ yhatT)
{
    __shared__ u32 sT[256 * 17];       // [col][i-pair], 17-dword rows (conflict-free)
    __shared__ float sM[32], sR[32];

    const int tid = threadIdx.x;
    const int nic = blockIdx.y;
    const int n   = nic >> 2, ic = nic & 3;
    const int c0  = blockIdx.x * 256;

    if (tid < 32) {
        float a = statsY[(n * CH + ic * 32 + tid) * 2 + 0];
        float b = statsY[(n * CH + ic * 32 + tid) * 2 + 1];
        float m = a * INV_PLANE;
        sM[tid] = m;
        sR[tid] = rsqrtf(b * INV_PLANE - m * m + EPSF);
    }
    __syncthreads();

    for (int idx = tid; idx < 4096; idx += 256) {
        int ip = idx >> 8;             // wave-uniform i-pair
        int c  = idx & 255;
        int i0 = ip * 2;
        int g0 = (n * CH + ic * 32 + i0) * PLANE + c0 + c;
        int g1 = g0 + PLANE;
        float va = fmaxf((bf2f(y0b[g0]) - sM[i0]) * sR[i0] + x[g0], 0.f);
        float vb = fmaxf((bf2f(y0b[g1]) - sM[i0 + 1]) * sR[i0 + 1] + x[g1], 0.f);
        sT[c * 17 + ip] = (u32)f2bf(va) | ((u32)f2bf(vb) << 16);
    }
    __syncthreads();

    u32* outd = (u32*)yhatT;
    int obase = (nic * PLANE + c0) * 16;          // 16 dwords (=32 bf16) per col
    for (int idx = tid; idx < 4096; idx += 256)
        outd[obase + idx] = sT[(idx >> 4) * 17 + (idx & 15)];
}

// ---------------- K3: TCN conv via bf16 MFMA ----------------
// grid (50, 32): blockIdx.x = 128-flat-col block, blockIdx.y = n. 256 threads = 4 waves.
// Output 128 o x 128 cols; K-loop: 4 i-chunks (32 i) x 5 taps; tap shift = 25*(tap-4) flat cols.
__global__ __launch_bounds__(256) void k3_mfma(
    const u16* __restrict__ yhatT, const u16* __restrict__ Wt_b,
    const float* __restrict__ bt,
    float* __restrict__ zout, float* __restrict__ statsZ)
{
    __shared__ __attribute__((aligned(16))) char lds[57344];   // sB[16384] + sA[40960]
    char* const sB = lds;            // [row 0..227][32 i] bf16, row = flat col - (c0-100)
    char* const sA = lds + 16384;    // [tap][o 128][32 i] bf16

    const int tid  = threadIdx.x;
    const int wave = tid >> 6;
    const int lane = tid & 63;
    const int l    = lane & 15;
    const int quad = lane >> 4;
    const int n    = blockIdx.y;
    const int blk  = blockIdx.x;
    const int c0   = blk * 128;
    const int wub  = tid & ~63;      // wave-uniform base for global_load_lds LDS dst

    floatx4 acc[2][8];
#pragma unroll
    for (int a = 0; a < 2; ++a)
#pragma unroll
        for (int b = 0; b < 8; ++b) acc[a][b] = (floatx4){0.f, 0.f, 0.f, 0.f};

    for (int ic = 0; ic < 4; ++ic) {
        __syncthreads();
        // stage A: 40960 B linear (2560 x 16B chunks)
        const char* asrc = (const char*)(Wt_b + ic * 20480);
#pragma unroll
        for (int it = 0; it < 10; ++it)
            gload_lds16(asrc + (it * 256 + tid) * 16, sA + (it * 256 + wub) * 16);
        // stage B: 228-col window [c0-100, c0+128), 64 B per col
        const char* bsrc = (const char*)(yhatT + (size_t)(n * 4 + ic) * (PLANE * 32));
        if (blk == 0) {
            // rows 100..227 <- cols 0..127 (512 chunks)
#pragma unroll
            for (int it = 0; it < 2; ++it)
                gload_lds16(bsrc + (it * 256 + tid) * 16, sB + 6400 + (it * 256 + wub) * 16);
            // rows 0..99: reflected (t_in<0 -> t=|t_in|), scalar staging
            const u32* bsrcd = (const u32*)bsrc;
            u32* sBd = (u32*)sB;
            for (int idx = tid; idx < 1600; idx += 256) {
                int r = idx >> 4, dw = idx & 15;
                int d = 100 - r;                  // 1..100
                int tref = (d + 24) / 25;         // = -t_in, 1..4
                int v = r % 25;
                sBd[idx] = bsrcd[(tref * 25 + v) * 16 + dw];
            }
        } else {
            // full linear window (1024 chunks; rows>=228 are pad, over-read stays in ws)
            const char* bsrc2 = bsrc + (size_t)(c0 - 100) * 64;
#pragma unroll
            for (int it = 0; it < 4; ++it)
                gload_lds16(bsrc2 + (it * 256 + tid) * 16, sB + (it * 256 + wub) * 16);
        }
        __syncthreads();
        // MFMA: per tap, 2 A-frags + 8 B-frags, 16 mfma
#pragma unroll
        for (int tap = 0; tap < KT; ++tap) {
            const short8 a0 = *(const short8*)(sA + tap * 8192 + (wave * 32      + l) * 64 + quad * 16);
            const short8 a1 = *(const short8*)(sA + tap * 8192 + (wave * 32 + 16 + l) * 64 + quad * 16);
#pragma unroll
            for (int ct = 0; ct < 8; ++ct) {
                const short8 b = *(const short8*)(sB + (ct * 16 + l + tap * 25) * 64 + quad * 16);
                acc[0][ct] = __builtin_amdgcn_mfma_f32_16x16x32_bf16(a0, b, acc[0][ct], 0, 0, 0);
                acc[1][ct] = __builtin_amdgcn_mfma_f32_16x16x32_bf16(a1, b, acc[1][ct], 0, 0, 0);
            }
        }
    }

    // epilogue: bias + store + stats (C/D: col=lane&15, row=quad*4+reg)
#pragma unroll
    for (int ot = 0; ot < 2; ++ot) {
#pragma unroll
        for (int reg = 0; reg < 4; ++reg) {
            const int o = wave * 32 + ot * 16 + quad * 4 + reg;
            const float bias = bt[o];
            float s1 = 0.f, s2 = 0.f;
            float* zp = zout + (size_t)(n * CH + o) * PLANE + c0 + l;
#pragma unroll
            for (int ct = 0; ct < 8; ++ct) {
                float val = acc[ot][ct][reg] + bias;
                zp[ct * 16] = val;
                s1 += val; s2 += val * val;
            }
#pragma unroll
            for (int m = 1; m <= 8; m <<= 1) {
                s1 += __shfl_xor(s1, m, 64);
                s2 += __shfl_xor(s2, m, 64);
            }
            if (l == 0) {
                atomicAdd(&statsZ[(n * CH + o) * 2 + 0], s1);
                atomicAdd(&statsZ[(n * CH + o) * 2 + 1], s2);
            }
        }
    }
}

// ---------------- K4: out = relu(inorm(z0) + x), in-place on d_out ----------------
__global__ __launch_bounds__(256) void k4_final(
    const float* __restrict__ x, const float* __restrict__ statsZ,
    float* __restrict__ out)
{
    int i4 = blockIdx.x * 256 + threadIdx.x;      // 6,553,600 float4s
    int p  = i4 / 1600;
    float a = statsZ[p * 2 + 0], b = statsZ[p * 2 + 1];
    float m = a * INV_PLANE;
    float r = rsqrtf(b * INV_PLANE - m * m + EPSF);
    float4 z  = ((const float4*)out)[i4];
    float4 xv = ((const float4*)x)[i4];
    float4 o;
    o.x = fmaxf((z.x - m) * r + xv.x, 0.f);
    o.y = fmaxf((z.y - m) * r + xv.y, 0.f);
    o.z = fmaxf((z.z - m) * r + xv.z, 0.f);
    o.w = fmaxf((z.w - m) * r + xv.w, 0.f);
    ((float4*)out)[i4] = o;
}

extern "C" void kernel_launch(void* const* d_in, const int* in_sizes, int n_in,
                              void* d_out, int out_size, void* d_ws, size_t ws_size,
                              hipStream_t stream) {
    const float* x  = (const float*)d_in[0];
    const float* PA = (const float*)d_in[1];
    const float* Wd = (const float*)d_in[2];
    const float* bd = (const float*)d_in[3];
    const float* Wt = (const float*)d_in[4];
    const float* bt = (const float*)d_in[5];
    float* out = (float*)d_out;

    char* wsb = (char*)d_ws;
    u16*   y0b    = (u16*)(wsb);                   // 52,428,800 B
    u16*   yhatT  = (u16*)(wsb + 52428800);        // 52,428,800 B
    float* statsY = (float*)(wsb + 104857600);     // 32,768 B
    float* statsZ = (float*)(wsb + 104890368);     // 32,768 B
    float* WdT    = (float*)(wsb + 104923136);     // 65,536 B
    u16*   Wt_b   = (u16*)(wsb + 104988672);       // 163,840 B  (end ~105.2 MB)

    k0_init<<<dim3(448), dim3(256), 0, stream>>>(Wd, Wt, statsY, statsZ, WdT, Wt_b);
    k1_gcn<<<dim3(64, 32), dim3(256), 0, stream>>>(x, PA, WdT, bd, y0b, statsY);
    k2_yhat<<<dim3(25, 128), dim3(256), 0, stream>>>(y0b, x, statsY, yhatT);
    k3_mfma<<<dim3(50, 32), dim3(256), 0, stream>>>(yhatT, Wt_b, bt, out, statsZ);
    k4_final<<<dim3(25600), dim3(256), 0, stream>>>(x, statsZ, out);
}

// Round 3
// 382.927 us; speedup vs baseline: 3.9031x; 2.2339x over previous
//
#include <hip/hip_runtime.h>

// GCN-TCN unit. All GEMM-shaped work on bf16 MFMA; elementwise memory-bound.
// Shapes: N=32, C=128, T=256, V=25, K=5.
//
//   k0 : init stats, Wd -> WdB bf16 [cc][o][c32], Wt -> Wt_b bf16 [ic][tap][o][i32]
//   k1a: g = x@PA -> gT bf16 [n][cc][col][c32]      (memory-bound transform)
//   k1b: y0 = Wd@g + bd -> y0b bf16 [n][o][col] + statsY   (MFMA, K=128)
//   k2 : yhat = relu(inorm(y0)+x) -> yhatT bf16 [n][ic][col][i32]  (aliases gT)
//   k3 : z = conv(yhat) + bt -> d_out fp32 + statsZ          (MFMA, K=640)
//   k4 : out = relu(inorm(z)+x) in-place

typedef unsigned short u16;
typedef unsigned int   u32;

using short8  = __attribute__((ext_vector_type(8))) short;
using floatx4 = __attribute__((ext_vector_type(4))) float;

#define NBATCH 32
#define CH     128
#define TDIM   256
#define VDIM   25
#define KT     5
#define PLANE  6400
#define EPSF   1e-5f
#define INV_PLANE (1.0f/6400.0f)

__device__ __forceinline__ u16 f2bf(float f) {          // RNE fp32 -> bf16
    u32 u = __float_as_uint(f);
    return (u16)((u + 0x7fffu + ((u >> 16) & 1u)) >> 16);
}
__device__ __forceinline__ float bf2f(u16 h) {
    return __uint_as_float(((u32)h) << 16);
}
__device__ __forceinline__ void gload_lds16(const void* g, void* l) {
    __builtin_amdgcn_global_load_lds(
        (const __attribute__((address_space(1))) u32*)g,
        (__attribute__((address_space(3))) u32*)l, 16, 0, 0);
}

// ---------------- K0: init stats + weight repack ----------------
__global__ __launch_bounds__(256) void k0_init(
    const float* __restrict__ Wd, const float* __restrict__ Wt,
    float* __restrict__ statsY, float* __restrict__ statsZ,
    u16* __restrict__ WdB, u16* __restrict__ Wt_b)
{
    int i = blockIdx.x * 256 + threadIdx.x;       // grid covers exactly 114688
    if (i < 8192) {
        statsY[i] = 0.f;
    } else if (i < 16384) {
        statsZ[i - 8192] = 0.f;
    } else if (i < 32768) {
        int j  = i - 16384;                       // WdB[cc][o][cl] = Wd[o][cc*32+cl]
        int cl = j & 31;
        int o  = (j >> 5) & 127;
        int cc = j >> 12;
        WdB[j] = f2bf(Wd[o * CH + cc * 32 + cl]);
    } else {
        int j  = i - 32768;                       // Wt_b[ic][tap][o][il]
        int il = j & 31;
        int o  = (j >> 5) & 127;
        int r2 = j >> 12;                         // ic*5 + tap
        int tap = r2 % KT;
        int ic  = r2 / KT;
        Wt_b[j] = f2bf(Wt[(o * CH + ic * 32 + il) * KT + tap]);
    }
}

// ---------------- K1a: g = x@PA -> gT bf16 [n][cc][col][c32] ----------------
// grid (16, 128): blockIdx.x = 400-col chunk (16 t-rows), blockIdx.y = n*4+cc.
// Thread (cl = tid>>3, tl = tid&7) owns t-rows {2tl, 2tl+1} of channel cl.
__global__ __launch_bounds__(256) void k1a_gcn(
    const float* __restrict__ x, const float* __restrict__ PA,
    u16* __restrict__ gT)
{
    __shared__ __attribute__((aligned(16))) u32 sG[6800];   // 400 rows x 17 dwords (pad)
    __shared__ float sPA[625];

    const int tid   = threadIdx.x;
    const int nic   = blockIdx.y;
    const int chunk = blockIdx.x;
    const int c0    = chunk * 400;
    const int cl    = tid >> 3;
    const int tl    = tid & 7;

    for (int i = tid; i < 625; i += 256) sPA[i] = PA[i];

    // 50 x-floats (2 t-rows) straight from global, float2 (8B-aligned)
    const float* xrow = x + (size_t)(nic * 32 + cl) * PLANE + c0 + tl * 50;
    float xr[50];
#pragma unroll
    for (int w = 0; w < 25; ++w) {
        float2 t2 = *(const float2*)(xrow + 2 * w);
        xr[2 * w]     = t2.x;
        xr[2 * w + 1] = t2.y;
    }
    __syncthreads();

    u16* sG16 = (u16*)sG;
#pragma unroll
    for (int v = 0; v < VDIM; ++v) {
        float g0 = 0.f, g1 = 0.f;
#pragma unroll
        for (int w = 0; w < VDIM; ++w) {
            float p = sPA[w * VDIM + v];          // wave-uniform broadcast
            g0 += xr[w] * p;
            g1 += xr[25 + w] * p;
        }
        int r0 = tl * 50 + v;                     // local col = t_local*25 + v
        sG16[r0 * 34 + cl]        = f2bf(g0);
        sG16[(r0 + 25) * 34 + cl] = f2bf(g1);
    }
    __syncthreads();

    u32* outd = (u32*)gT;
    const size_t ob = ((size_t)nic * PLANE + c0) * 16;  // 16 dwords per col
    for (int j = tid; j < 6400; j += 256) {
        int r = j >> 4, dw = j & 15;
        outd[ob + j] = sG[r * 17 + dw];
    }
}

// ---------------- K1b: y0 = Wd@g + bd via bf16 MFMA, K=128 ----------------
// grid (50, 32): blockIdx.x = 128-col block, blockIdx.y = n. 256 threads = 4 waves.
__global__ __launch_bounds__(256) void k1b_mfma(
    const u16* __restrict__ gT, const u16* __restrict__ WdB,
    const float* __restrict__ bd,
    u16* __restrict__ y0b, float* __restrict__ statsY)
{
    __shared__ __attribute__((aligned(16))) char lds[65536];
    char* const sA = lds;            // [cc4][o128][c32] bf16 = 32KB
    char* const sB = lds + 32768;    // [cc4][col128][c32] bf16 = 32KB

    const int tid  = threadIdx.x;
    const int wave = tid >> 6;
    const int lane = tid & 63;
    const int l    = lane & 15;
    const int quad = lane >> 4;
    const int n    = blockIdx.y;
    const int c0   = blockIdx.x * 128;
    const int wub  = tid & ~63;

    // stage A: full WdB, 32KB linear
#pragma unroll
    for (int it = 0; it < 8; ++it)
        gload_lds16((const char*)WdB + (it * 256 + tid) * 16, sA + (it * 256 + wub) * 16);
    // stage B: per cc, 128 cols x 64B contiguous
#pragma unroll
    for (int cc = 0; cc < 4; ++cc) {
        const char* bsrc = (const char*)gT + ((size_t)(n * 4 + cc) * PLANE + c0) * 64;
#pragma unroll
        for (int it = 0; it < 2; ++it)
            gload_lds16(bsrc + (it * 256 + tid) * 16, sB + cc * 8192 + (it * 256 + wub) * 16);
    }
    __syncthreads();

    floatx4 acc[2][8];
#pragma unroll
    for (int a = 0; a < 2; ++a)
#pragma unroll
        for (int b = 0; b < 8; ++b) acc[a][b] = (floatx4){0.f, 0.f, 0.f, 0.f};

#pragma unroll
    for (int cc = 0; cc < 4; ++cc) {
        const short8 a0 = *(const short8*)(sA + cc * 8192 + (wave * 32      + l) * 64 + quad * 16);
        const short8 a1 = *(const short8*)(sA + cc * 8192 + (wave * 32 + 16 + l) * 64 + quad * 16);
#pragma unroll
        for (int ct = 0; ct < 8; ++ct) {
            const short8 b = *(const short8*)(sB + cc * 8192 + (ct * 16 + l) * 64 + quad * 16);
            acc[0][ct] = __builtin_amdgcn_mfma_f32_16x16x32_bf16(a0, b, acc[0][ct], 0, 0, 0);
            acc[1][ct] = __builtin_amdgcn_mfma_f32_16x16x32_bf16(a1, b, acc[1][ct], 0, 0, 0);
        }
    }

    // epilogue: bias + bf16 store + stats (C/D: col=lane&15, row=quad*4+reg)
#pragma unroll
    for (int ot = 0; ot < 2; ++ot) {
#pragma unroll
        for (int reg = 0; reg < 4; ++reg) {
            const int o = wave * 32 + ot * 16 + quad * 4 + reg;
            const float bias = bd[o];
            float s1 = 0.f, s2 = 0.f;
            u16* yp = y0b + (size_t)(n * CH + o) * PLANE + c0 + l;
#pragma unroll
            for (int ct = 0; ct < 8; ++ct) {
                float val = acc[ot][ct][reg] + bias;
                yp[ct * 16] = f2bf(val);
                s1 += val; s2 += val * val;
            }
#pragma unroll
            for (int m = 1; m <= 8; m <<= 1) {
                s1 += __shfl_xor(s1, m, 64);
                s2 += __shfl_xor(s2, m, 64);
            }
            if (l == 0) {
                atomicAdd(&statsY[(n * CH + o) * 2 + 0], s1);
                atomicAdd(&statsY[(n * CH + o) * 2 + 1], s2);
            }
        }
    }
}

// ---------------- K2: yhat = relu(inorm(y0)+x) -> bf16 transposed [n][ic][col][i32] ----------------
__global__ __launch_bounds__(256) void k2_yhat(
    const u16* __restrict__ y0b, const float* __restrict__ x,
    const float* __restrict__ statsY, u16* __restrict__ yhatT)
{
    __shared__ u32 sT[256 * 17];
    __shared__ float sM[32], sR[32];

    const int tid = threadIdx.x;
    const int nic = blockIdx.y;
    const int n   = nic >> 2, ic = nic & 3;
    const int c0  = blockIdx.x * 256;

    if (tid < 32) {
        float a = statsY[(n * CH + ic * 32 + tid) * 2 + 0];
        float b = statsY[(n * CH + ic * 32 + tid) * 2 + 1];
        float m = a * INV_PLANE;
        sM[tid] = m;
        sR[tid] = rsqrtf(b * INV_PLANE - m * m + EPSF);
    }
    __syncthreads();

    for (int idx = tid; idx < 4096; idx += 256) {
        int ip = idx >> 8;
        int c  = idx & 255;
        int i0 = ip * 2;
        int g0 = (n * CH + ic * 32 + i0) * PLANE + c0 + c;
        int g1 = g0 + PLANE;
        float va = fmaxf((bf2f(y0b[g0]) - sM[i0]) * sR[i0] + x[g0], 0.f);
        float vb = fmaxf((bf2f(y0b[g1]) - sM[i0 + 1]) * sR[i0 + 1] + x[g1], 0.f);
        sT[c * 17 + ip] = (u32)f2bf(va) | ((u32)f2bf(vb) << 16);
    }
    __syncthreads();

    u32* outd = (u32*)yhatT;
    int obase = (nic * PLANE + c0) * 16;
    for (int idx = tid; idx < 4096; idx += 256)
        outd[obase + idx] = sT[(idx >> 4) * 17 + (idx & 15)];
}

// ---------------- K3: TCN conv via bf16 MFMA ----------------
__global__ __launch_bounds__(256) void k3_mfma(
    const u16* __restrict__ yhatT, const u16* __restrict__ Wt_b,
    const float* __restrict__ bt,
    float* __restrict__ zout, float* __restrict__ statsZ)
{
    __shared__ __attribute__((aligned(16))) char lds[57344];   // sB[16384] + sA[40960]
    char* const sB = lds;            // [row 0..227][32 i] bf16, row = flat col - (c0-100)
    char* const sA = lds + 16384;    // [tap][o 128][32 i] bf16

    const int tid  = threadIdx.x;
    const int wave = tid >> 6;
    const int lane = tid & 63;
    const int l    = lane & 15;
    const int quad = lane >> 4;
    const int n    = blockIdx.y;
    const int blk  = blockIdx.x;
    const int c0   = blk * 128;
    const int wub  = tid & ~63;

    floatx4 acc[2][8];
#pragma unroll
    for (int a = 0; a < 2; ++a)
#pragma unroll
        for (int b = 0; b < 8; ++b) acc[a][b] = (floatx4){0.f, 0.f, 0.f, 0.f};

    for (int ic = 0; ic < 4; ++ic) {
        __syncthreads();
        const char* asrc = (const char*)(Wt_b + ic * 20480);
#pragma unroll
        for (int it = 0; it < 10; ++it)
            gload_lds16(asrc + (it * 256 + tid) * 16, sA + (it * 256 + wub) * 16);
        const char* bsrc = (const char*)(yhatT + (size_t)(n * 4 + ic) * (PLANE * 32));
        if (blk == 0) {
#pragma unroll
            for (int it = 0; it < 2; ++it)
                gload_lds16(bsrc + (it * 256 + tid) * 16, sB + 6400 + (it * 256 + wub) * 16);
            const u32* bsrcd = (const u32*)bsrc;
            u32* sBd = (u32*)sB;
            for (int idx = tid; idx < 1600; idx += 256) {
                int r = idx >> 4, dw = idx & 15;
                int d = 100 - r;
                int tref = (d + 24) / 25;
                int v = r % 25;
                sBd[idx] = bsrcd[(tref * 25 + v) * 16 + dw];
            }
        } else {
            const char* bsrc2 = bsrc + (size_t)(c0 - 100) * 64;
#pragma unroll
            for (int it = 0; it < 4; ++it)
                gload_lds16(bsrc2 + (it * 256 + tid) * 16, sB + (it * 256 + wub) * 16);
        }
        __syncthreads();
#pragma unroll
        for (int tap = 0; tap < KT; ++tap) {
            const short8 a0 = *(const short8*)(sA + tap * 8192 + (wave * 32      + l) * 64 + quad * 16);
            const short8 a1 = *(const short8*)(sA + tap * 8192 + (wave * 32 + 16 + l) * 64 + quad * 16);
#pragma unroll
            for (int ct = 0; ct < 8; ++ct) {
                const short8 b = *(const short8*)(sB + (ct * 16 + l + tap * 25) * 64 + quad * 16);
                acc[0][ct] = __builtin_amdgcn_mfma_f32_16x16x32_bf16(a0, b, acc[0][ct], 0, 0, 0);
                acc[1][ct] = __builtin_amdgcn_mfma_f32_16x16x32_bf16(a1, b, acc[1][ct], 0, 0, 0);
            }
        }
    }

#pragma unroll
    for (int ot = 0; ot < 2; ++ot) {
#pragma unroll
        for (int reg = 0; reg < 4; ++reg) {
            const int o = wave * 32 + ot * 16 + quad * 4 + reg;
            const float bias = bt[o];
            float s1 = 0.f, s2 = 0.f;
            float* zp = zout + (size_t)(n * CH + o) * PLANE + c0 + l;
#pragma unroll
            for (int ct = 0; ct < 8; ++ct) {
                float val = acc[ot][ct][reg] + bias;
                zp[ct * 16] = val;
                s1 += val; s2 += val * val;
            }
#pragma unroll
            for (int m = 1; m <= 8; m <<= 1) {
                s1 += __shfl_xor(s1, m, 64);
                s2 += __shfl_xor(s2, m, 64);
            }
            if (l == 0) {
                atomicAdd(&statsZ[(n * CH + o) * 2 + 0], s1);
                atomicAdd(&statsZ[(n * CH + o) * 2 + 1], s2);
            }
        }
    }
}

// ---------------- K4: out = relu(inorm(z0) + x), in-place on d_out ----------------
__global__ __launch_bounds__(256) void k4_final(
    const float* __restrict__ x, const float* __restrict__ statsZ,
    float* __restrict__ out)
{
    int i4 = blockIdx.x * 256 + threadIdx.x;      // 6,553,600 float4s
    int p  = i4 / 1600;
    float a = statsZ[p * 2 + 0], b = statsZ[p * 2 + 1];
    float m = a * INV_PLANE;
    float r = rsqrtf(b * INV_PLANE - m * m + EPSF);
    float4 z  = ((const float4*)out)[i4];
    float4 xv = ((const float4*)x)[i4];
    float4 o;
    o.x = fmaxf((z.x - m) * r + xv.x, 0.f);
    o.y = fmaxf((z.y - m) * r + xv.y, 0.f);
    o.z = fmaxf((z.z - m) * r + xv.z, 0.f);
    o.w = fmaxf((z.w - m) * r + xv.w, 0.f);
    ((float4*)out)[i4] = o;
}

extern "C" void kernel_launch(void* const* d_in, const int* in_sizes, int n_in,
                              void* d_out, int out_size, void* d_ws, size_t ws_size,
                              hipStream_t stream) {
    const float* x  = (const float*)d_in[0];
    const float* PA = (const float*)d_in[1];
    const float* Wd = (const float*)d_in[2];
    const float* bd = (const float*)d_in[3];
    const float* Wt = (const float*)d_in[4];
    const float* bt = (const float*)d_in[5];
    float* out = (float*)d_out;

    char* wsb = (char*)d_ws;
    u16*   y0b    = (u16*)(wsb);                   // 52,428,800 B
    u16*   gT     = (u16*)(wsb + 52428800);        // 52,428,800 B (aliased by yhatT)
    u16*   yhatT  = gT;                            //   gT consumed by k1b before k2 writes
    float* statsY = (float*)(wsb + 104857600);     // 32,768 B
    float* statsZ = (float*)(wsb + 104890368);     // 32,768 B
    u16*   WdB    = (u16*)(wsb + 104923136);       // 32,768 B
    u16*   Wt_b   = (u16*)(wsb + 104955904);       // 163,840 B  (end ~105.1 MB)

    k0_init<<<dim3(448), dim3(256), 0, stream>>>(Wd, Wt, statsY, statsZ, WdB, Wt_b);
    k1a_gcn<<<dim3(16, 128), dim3(256), 0, stream>>>(x, PA, gT);
    k1b_mfma<<<dim3(50, 32), dim3(256), 0, stream>>>(gT, WdB, bd, y0b, statsY);
    k2_yhat<<<dim3(25, 128), dim3(256), 0, stream>>>(y0b, x, statsY, yhatT);
    k3_mfma<<<dim3(50, 32), dim3(256), 0, stream>>>(yhatT, Wt_b, bt, out, statsZ);
    k4_final<<<dim3(25600), dim3(256), 0, stream>>>(x, statsZ, out);
}

// Round 4
// 375.089 us; speedup vs baseline: 3.9846x; 1.0209x over previous
//
#include <hip/hip_runtime.h>

// GCN-TCN unit. All GEMM-shaped work on bf16 MFMA; swizzled global layouts
// (chunk q of each 64B row stored at position q ^ (row&3)) kill LDS bank
// conflicts while keeping global_load_lds staging purely linear.
// Shapes: N=32, C=128, T=256, V=25, K=5.
//
//   k0 : init stats, Wd -> WdB bf16 [cc][o][c32]~swz(o), Wt -> Wt_b [ic][tap][o][i32]~swz(o)
//   k1a: g = x@PA -> gT bf16 [n][cc][col][c32]~swz(col)
//   k1b: y0 = Wd@g + bd -> y0b bf16 + statsY          (MFMA, K=128)
//   k2 : yhat = relu(inorm(y0)+x) -> yhatT ~swz(col)  (aliases gT)
//   k3 : z = conv(yhat) + bt -> zb bf16 (aliases y0b) + statsZ  (MFMA, K=640)
//   k4 : out = relu(inorm(z)+x) -> d_out fp32

typedef unsigned short u16;
typedef unsigned int   u32;

using short8  = __attribute__((ext_vector_type(8))) short;
using floatx4 = __attribute__((ext_vector_type(4))) float;

#define NBATCH 32
#define CH     128
#define TDIM   256
#define VDIM   25
#define KT     5
#define PLANE  6400
#define EPSF   1e-5f
#define INV_PLANE (1.0f/6400.0f)

__device__ __forceinline__ u16 f2bf(float f) {          // RNE fp32 -> bf16
    u32 u = __float_as_uint(f);
    return (u16)((u + 0x7fffu + ((u >> 16) & 1u)) >> 16);
}
__device__ __forceinline__ float bf2f(u16 h) {
    return __uint_as_float(((u32)h) << 16);
}
__device__ __forceinline__ void gload_lds16(const void* g, void* l) {
    __builtin_amdgcn_global_load_lds(
        (const __attribute__((address_space(1))) u32*)g,
        (__attribute__((address_space(3))) u32*)l, 16, 0, 0);
}

// ---------------- K0: init stats + weight repack (swizzled) ----------------
__global__ __launch_bounds__(256) void k0_init(
    const float* __restrict__ Wd, const float* __restrict__ Wt,
    float* __restrict__ statsY, float* __restrict__ statsZ,
    u16* __restrict__ WdB, u16* __restrict__ Wt_b)
{
    int i = blockIdx.x * 256 + threadIdx.x;       // grid covers exactly 114688
    if (i < 8192) {
        statsY[i] = 0.f;
    } else if (i < 16384) {
        statsZ[i - 8192] = 0.f;
    } else if (i < 32768) {
        int j  = i - 16384;                       // WdB[cc][o][stored c-slot]
        int sl = j & 31;                          // stored slot within row
        int o  = (j >> 5) & 127;
        int cc = j >> 12;
        int cl = (((sl >> 3) ^ (o & 3)) << 3) | (sl & 7);   // logical c-low
        WdB[j] = f2bf(Wd[o * CH + cc * 32 + cl]);
    } else {
        int j  = i - 32768;                       // Wt_b[ic][tap][o][stored i-slot]
        int sl = j & 31;
        int o  = (j >> 5) & 127;
        int r2 = j >> 12;                         // ic*5 + tap
        int tap = r2 % KT;
        int ic  = r2 / KT;
        int il = (((sl >> 3) ^ (o & 3)) << 3) | (sl & 7);
        Wt_b[j] = f2bf(Wt[(o * CH + ic * 32 + il) * KT + tap]);
    }
}

// ---------------- K1a: g = x@PA -> gT bf16 [n][cc][col][c32]~swz ----------------
// grid (16, 128): blockIdx.x = 400-col chunk (16 t-rows), blockIdx.y = n*4+cc.
__global__ __launch_bounds__(256) void k1a_gcn(
    const float* __restrict__ x, const float* __restrict__ PA,
    u16* __restrict__ gT)
{
    __shared__ __attribute__((aligned(16))) u32 sG[6800];   // 400 rows x 17 dwords (pad)
    __shared__ float sPA[625];

    const int tid   = threadIdx.x;
    const int nic   = blockIdx.y;
    const int chunk = blockIdx.x;
    const int c0    = chunk * 400;                // multiple of 4 -> swz key = local r
    const int cl    = tid >> 3;
    const int tl    = tid & 7;

    for (int i = tid; i < 625; i += 256) sPA[i] = PA[i];

    const float* xrow = x + (size_t)(nic * 32 + cl) * PLANE + c0 + tl * 50;
    float xr[50];
#pragma unroll
    for (int w = 0; w < 25; ++w) {
        float2 t2 = *(const float2*)(xrow + 2 * w);
        xr[2 * w]     = t2.x;
        xr[2 * w + 1] = t2.y;
    }
    __syncthreads();

    u16* sG16 = (u16*)sG;
#pragma unroll
    for (int v = 0; v < VDIM; ++v) {
        float g0 = 0.f, g1 = 0.f;
#pragma unroll
        for (int w = 0; w < VDIM; ++w) {
            float p = sPA[w * VDIM + v];          // wave-uniform broadcast
            g0 += xr[w] * p;
            g1 += xr[25 + w] * p;
        }
        int r0 = tl * 50 + v;
        sG16[r0 * 34 + cl]        = f2bf(g0);
        sG16[(r0 + 25) * 34 + cl] = f2bf(g1);
    }
    __syncthreads();

    u32* outd = (u32*)gT;
    const size_t ob = ((size_t)nic * PLANE + c0) * 16;
    for (int j = tid; j < 6400; j += 256) {
        int r = j >> 4, dw = j & 15;
        int q = dw >> 2, b = dw & 3;
        outd[ob + r * 16 + (((q ^ (r & 3)) << 2) | b)] = sG[r * 17 + dw];
    }
}

// ---------------- K1b: y0 = Wd@g + bd via bf16 MFMA, K=128 ----------------
// grid (50, 32): blockIdx.x = 128-col block, blockIdx.y = n. 256 threads = 4 waves.
__global__ __launch_bounds__(256) void k1b_mfma(
    const u16* __restrict__ gT, const u16* __restrict__ WdB,
    const float* __restrict__ bd,
    u16* __restrict__ y0b, float* __restrict__ statsY)
{
    __shared__ __attribute__((aligned(16))) char lds[65536];
    char* const sA = lds;            // [cc4][o128][c32] bf16 = 32KB (swz rows)
    char* const sB = lds + 32768;    // [cc4][col128][c32] bf16 = 32KB (swz rows)

    const int tid  = threadIdx.x;
    const int wave = tid >> 6;
    const int lane = tid & 63;
    const int l    = lane & 15;
    const int quad = lane >> 4;
    const int n    = blockIdx.y;
    const int c0   = blockIdx.x * 128;            // mult of 4
    const int wub  = tid & ~63;

#pragma unroll
    for (int it = 0; it < 8; ++it)
        gload_lds16((const char*)WdB + (it * 256 + tid) * 16, sA + (it * 256 + wub) * 16);
#pragma unroll
    for (int cc = 0; cc < 4; ++cc) {
        const char* bsrc = (const char*)gT + ((size_t)(n * 4 + cc) * PLANE + c0) * 64;
#pragma unroll
        for (int it = 0; it < 2; ++it)
            gload_lds16(bsrc + (it * 256 + tid) * 16, sB + cc * 8192 + (it * 256 + wub) * 16);
    }
    __syncthreads();

    floatx4 acc[2][8];
#pragma unroll
    for (int a = 0; a < 2; ++a)
#pragma unroll
        for (int b = 0; b < 8; ++b) acc[a][b] = (floatx4){0.f, 0.f, 0.f, 0.f};

    const int swzA = (quad ^ (l & 3)) << 4;       // row key = o&3 = l&3 / col key = l&3
#pragma unroll
    for (int cc = 0; cc < 4; ++cc) {
        const short8 a0 = *(const short8*)(sA + cc * 8192 + (wave * 32      + l) * 64 + swzA);
        const short8 a1 = *(const short8*)(sA + cc * 8192 + (wave * 32 + 16 + l) * 64 + swzA);
#pragma unroll
        for (int ct = 0; ct < 8; ++ct) {
            const short8 b = *(const short8*)(sB + cc * 8192 + (ct * 16 + l) * 64 + swzA);
            acc[0][ct] = __builtin_amdgcn_mfma_f32_16x16x32_bf16(a0, b, acc[0][ct], 0, 0, 0);
            acc[1][ct] = __builtin_amdgcn_mfma_f32_16x16x32_bf16(a1, b, acc[1][ct], 0, 0, 0);
        }
    }

#pragma unroll
    for (int ot = 0; ot < 2; ++ot) {
#pragma unroll
        for (int reg = 0; reg < 4; ++reg) {
            const int o = wave * 32 + ot * 16 + quad * 4 + reg;
            const float bias = bd[o];
            float s1 = 0.f, s2 = 0.f;
            u16* yp = y0b + (size_t)(n * CH + o) * PLANE + c0 + l;
#pragma unroll
            for (int ct = 0; ct < 8; ++ct) {
                float val = acc[ot][ct][reg] + bias;
                yp[ct * 16] = f2bf(val);
                s1 += val; s2 += val * val;
            }
#pragma unroll
            for (int m = 1; m <= 8; m <<= 1) {
                s1 += __shfl_xor(s1, m, 64);
                s2 += __shfl_xor(s2, m, 64);
            }
            if (l == 0) {
                atomicAdd(&statsY[(n * CH + o) * 2 + 0], s1);
                atomicAdd(&statsY[(n * CH + o) * 2 + 1], s2);
            }
        }
    }
}

// ---------------- K2: yhat = relu(inorm(y0)+x) -> yhatT bf16 ~swz ----------------
__global__ __launch_bounds__(256) void k2_yhat(
    const u16* __restrict__ y0b, const float* __restrict__ x,
    const float* __restrict__ statsY, u16* __restrict__ yhatT)
{
    __shared__ u32 sT[256 * 17];
    __shared__ float sM[32], sR[32];

    const int tid = threadIdx.x;
    const int nic = blockIdx.y;
    const int n   = nic >> 2, ic = nic & 3;
    const int c0  = blockIdx.x * 256;             // mult of 4

    if (tid < 32) {
        float a = statsY[(n * CH + ic * 32 + tid) * 2 + 0];
        float b = statsY[(n * CH + ic * 32 + tid) * 2 + 1];
        float m = a * INV_PLANE;
        sM[tid] = m;
        sR[tid] = rsqrtf(b * INV_PLANE - m * m + EPSF);
    }
    __syncthreads();

    for (int idx = tid; idx < 4096; idx += 256) {
        int ip = idx >> 8;
        int c  = idx & 255;
        int i0 = ip * 2;
        int g0 = (n * CH + ic * 32 + i0) * PLANE + c0 + c;
        int g1 = g0 + PLANE;
        float va = fmaxf((bf2f(y0b[g0]) - sM[i0]) * sR[i0] + x[g0], 0.f);
        float vb = fmaxf((bf2f(y0b[g1]) - sM[i0 + 1]) * sR[i0 + 1] + x[g1], 0.f);
        sT[c * 17 + ip] = (u32)f2bf(va) | ((u32)f2bf(vb) << 16);
    }
    __syncthreads();

    u32* outd = (u32*)yhatT;
    int obase = (nic * PLANE + c0) * 16;
    for (int idx = tid; idx < 4096; idx += 256) {
        int r = idx >> 4, dw = idx & 15;
        int q = dw >> 2, b = dw & 3;
        outd[obase + r * 16 + (((q ^ (r & 3)) << 2) | b)] = sT[r * 17 + dw];
    }
}

// ---------------- K3: TCN conv via bf16 MFMA, 128o x 256c blocks ----------------
// grid (25, 32): blockIdx.x = 256-col block, blockIdx.y = n. 256 threads = 4 waves.
// Wave (wr, wc) owns 64 o x 128 cols: 12 ds_read per 32 MFMA per tap.
__global__ __launch_bounds__(256, 2) void k3_mfma(
    const u16* __restrict__ yhatT, const u16* __restrict__ Wt_b,
    const float* __restrict__ bt,
    u16* __restrict__ zb, float* __restrict__ statsZ)
{
    __shared__ __attribute__((aligned(16))) char lds[65536];
    char* const sB = lds;            // [row 0..384)[32 i] bf16, row = flat col - (c0-100)
    char* const sA = lds + 24576;    // [tap][o 128][32 i] bf16 = 40960 B

    const int tid  = threadIdx.x;
    const int wave = tid >> 6;
    const int wr   = wave >> 1;      // o 64-half
    const int wc   = wave & 1;       // col 128-half
    const int lane = tid & 63;
    const int l    = lane & 15;
    const int quad = lane >> 4;
    const int n    = blockIdx.y;
    const int blk  = blockIdx.x;
    const int c0   = blk * 256;
    const int wub  = tid & ~63;

    floatx4 acc[4][8];
#pragma unroll
    for (int a = 0; a < 4; ++a)
#pragma unroll
        for (int b = 0; b < 8; ++b) acc[a][b] = (floatx4){0.f, 0.f, 0.f, 0.f};

    for (int ic = 0; ic < 4; ++ic) {
        __syncthreads();
        // stage A: 40960 B linear
        const char* asrc = (const char*)(Wt_b + ic * 20480);
#pragma unroll
        for (int it = 0; it < 10; ++it)
            gload_lds16(asrc + (it * 256 + tid) * 16, sA + (it * 256 + wub) * 16);
        // stage B: rows [0,384) <-> flat cols [c0-100, c0+284)
        const char* bsrc = (const char*)(yhatT + (size_t)(n * 4 + ic) * (PLANE * 32));
        if (blk == 0) {
            // rows 100..356 <- cols 0..256 linear
#pragma unroll
            for (int it = 0; it < 4; ++it)
                gload_lds16(bsrc + (it * 256 + tid) * 16, sB + 6400 + (it * 256 + wub) * 16);
            // rows 0..100: reflected (swizzle-aware copy)
            const u32* bsrcd = (const u32*)bsrc;
            u32* sBd = (u32*)sB;
            for (int idx = tid; idx < 1600; idx += 256) {
                int r = idx >> 4, dw = idx & 15;
                int q = dw >> 2, b = dw & 3;
                int d = 100 - r;
                int tref = (d + 24) / 25;
                int v = r % 25;
                int sc = tref * 25 + v;
                sBd[r * 16 + (((q ^ (r & 3)) << 2) | b)] =
                    bsrcd[sc * 16 + (((q ^ (sc & 3)) << 2) | b)];
            }
        } else {
            const char* bsrc2 = bsrc + (size_t)(c0 - 100) * 64;
#pragma unroll
            for (int it = 0; it < 6; ++it)   // rows 0..384 (356..384 staged but unused)
                gload_lds16(bsrc2 + (it * 256 + tid) * 16, sB + (it * 256 + wub) * 16);
        }
        __syncthreads();
#pragma unroll
        for (int tap = 0; tap < KT; ++tap) {
            short8 af[4];
#pragma unroll
            for (int ot = 0; ot < 4; ++ot) {
                int ro = wr * 64 + ot * 16 + l;   // key ro&3 = l&3
                af[ot] = *(const short8*)(sA + tap * 8192 + ro * 64 + ((quad ^ (l & 3)) << 4));
            }
#pragma unroll
            for (int ct = 0; ct < 8; ++ct) {
                int r = wc * 128 + ct * 16 + l + tap * 25;
                const short8 b = *(const short8*)(sB + r * 64 + ((quad ^ (r & 3)) << 4));
#pragma unroll
                for (int ot = 0; ot < 4; ++ot)
                    acc[ot][ct] = __builtin_amdgcn_mfma_f32_16x16x32_bf16(af[ot], b, acc[ot][ct], 0, 0, 0);
            }
        }
    }

    // epilogue: bias + bf16 store + stats (C/D: col=lane&15, row=quad*4+reg)
#pragma unroll
    for (int ot = 0; ot < 4; ++ot) {
#pragma unroll
        for (int reg = 0; reg < 4; ++reg) {
            const int o = wr * 64 + ot * 16 + quad * 4 + reg;
            const float bias = bt[o];
            float s1 = 0.f, s2 = 0.f;
            u16* zp = zb + (size_t)(n * CH + o) * PLANE + c0 + wc * 128 + l;
#pragma unroll
            for (int ct = 0; ct < 8; ++ct) {
                float val = acc[ot][ct][reg] + bias;
                zp[ct * 16] = f2bf(val);
                s1 += val; s2 += val * val;
            }
#pragma unroll
            for (int m = 1; m <= 8; m <<= 1) {
                s1 += __shfl_xor(s1, m, 64);
                s2 += __shfl_xor(s2, m, 64);
            }
            if (l == 0) {
                atomicAdd(&statsZ[(n * CH + o) * 2 + 0], s1);
                atomicAdd(&statsZ[(n * CH + o) * 2 + 1], s2);
            }
        }
    }
}

// ---------------- K4: out = relu(inorm(zb) + x) -> d_out ----------------
__global__ __launch_bounds__(256) void k4_final(
    const u16* __restrict__ zb, const float* __restrict__ x,
    const float* __restrict__ statsZ, float* __restrict__ out)
{
    int g = blockIdx.x * 256 + threadIdx.x;       // 3,276,800 threads x 8 elems
    int p = g / 800;
    float a = statsZ[p * 2 + 0], b = statsZ[p * 2 + 1];
    float m = a * INV_PLANE;
    float r = rsqrtf(b * INV_PLANE - m * m + EPSF);
    short8 zv = *(const short8*)(zb + (size_t)g * 8);
    const float4* xp = (const float4*)x + (size_t)g * 2;
    float4 x0 = xp[0], x1 = xp[1];
    float4 o0, o1;
    o0.x = fmaxf((bf2f((u16)zv[0]) - m) * r + x0.x, 0.f);
    o0.y = fmaxf((bf2f((u16)zv[1]) - m) * r + x0.y, 0.f);
    o0.z = fmaxf((bf2f((u16)zv[2]) - m) * r + x0.z, 0.f);
    o0.w = fmaxf((bf2f((u16)zv[3]) - m) * r + x0.w, 0.f);
    o1.x = fmaxf((bf2f((u16)zv[4]) - m) * r + x1.x, 0.f);
    o1.y = fmaxf((bf2f((u16)zv[5]) - m) * r + x1.y, 0.f);
    o1.z = fmaxf((bf2f((u16)zv[6]) - m) * r + x1.z, 0.f);
    o1.w = fmaxf((bf2f((u16)zv[7]) - m) * r + x1.w, 0.f);
    float4* op = (float4*)out + (size_t)g * 2;
    op[0] = o0;
    op[1] = o1;
}

extern "C" void kernel_launch(void* const* d_in, const int* in_sizes, int n_in,
                              void* d_out, int out_size, void* d_ws, size_t ws_size,
                              hipStream_t stream) {
    const float* x  = (const float*)d_in[0];
    const float* PA = (const float*)d_in[1];
    const float* Wd = (const float*)d_in[2];
    const float* bd = (const float*)d_in[3];
    const float* Wt = (const float*)d_in[4];
    const float* bt = (const float*)d_in[5];
    float* out = (float*)d_out;

    char* wsb = (char*)d_ws;
    u16*   y0b    = (u16*)(wsb);                   // 52,428,800 B (aliased by zb)
    u16*   zb     = y0b;                           //   y0b consumed by k2 before k3 writes
    u16*   gT     = (u16*)(wsb + 52428800);        // 52,428,800 B (aliased by yhatT)
    u16*   yhatT  = gT;                            //   gT consumed by k1b before k2 writes
    float* statsY = (float*)(wsb + 104857600);     // 32,768 B
    float* statsZ = (float*)(wsb + 104890368);     // 32,768 B
    u16*   WdB    = (u16*)(wsb + 104923136);       // 32,768 B
    u16*   Wt_b   = (u16*)(wsb + 104955904);       // 163,840 B

    k0_init<<<dim3(448), dim3(256), 0, stream>>>(Wd, Wt, statsY, statsZ, WdB, Wt_b);
    k1a_gcn<<<dim3(16, 128), dim3(256), 0, stream>>>(x, PA, gT);
    k1b_mfma<<<dim3(50, 32), dim3(256), 0, stream>>>(gT, WdB, bd, y0b, statsY);
    k2_yhat<<<dim3(25, 128), dim3(256), 0, stream>>>(y0b, x, statsY, yhatT);
    k3_mfma<<<dim3(25, 32), dim3(256), 0, stream>>>(yhatT, Wt_b, bt, zb, statsZ);
    k4_final<<<dim3(12800), dim3(256), 0, stream>>>(zb, x, statsZ, out);
}